// Round 9
// baseline (38.023 us; speedup 1.0000x reference)
//
#include <hip/hip_runtime.h>

// YOLO layer: input [B=16, A*C=255, G=76, G=76] f32, anchors [3,2] f32.
// Output [B, A*G*G=17328, C=85] f32.
//   c=0: (sigmoid+gx)*8, c=1: (sigmoid+gy)*8, c=2: exp*aw, c=3: exp*ah,
//   c>=4: sigmoid   (anchor/stride scaling folded: (e^w * aw/8)*8 == e^w*aw)
//
// R7 base (35.9us) + 2-deep register prefetch pipeline:
//   R7's loads were issued after barrier A and consumed at the next
//   transform head (~400 cyc cover < ~900 cyc HBM latency). Now two named
//   register buffers va/vb (static indexing) in a 2x-unrolled persistent
//   loop: tile g+GRID's loads issue BEFORE transform(g) -> a full
//   transform+store+2-barrier phase (~800-1000 cyc) hides the latency.
//   vmcnt FIFO ordering keeps the counted wait for va from draining vb.
// Lessons kept: __syncthreads (R4), plain stores (R5), HIP float4 +
// per-tile anchor loads (R6), fast v_exp/v_rcp transcendentals (R7).

#define GDIM 76
#define GG 5776            // 76*76 (divisible by 4)
#define NA 3
#define NCH 85
#define TILE 64            // spatial positions per block-tile
#define THREADS 256        // 4 waves
#define LOAD_UNITS (NCH * (TILE / 4))  // 1360 float4 units per tile
#define LITERS 6                       // ceil(1360/256)
#define TPB 91                         // tiles per (b,a): ceil(5776/64)
#define NT (TPB * NA * 16)             // 4368 total tiles
#define GRID 1792                      // 7 blocks/CU * 256 CUs (LDS cap)

__device__ __forceinline__ float fast_sigmoid(float x) {
    // 1/(1+exp(-x)): v_exp_f32 + v_add + v_rcp_f32. ~2 ulp; threshold ~496.
    return __builtin_amdgcn_rcpf(1.0f + __expf(-x));
}

__global__ __launch_bounds__(THREADS) void yolo_kernel(
    const float* __restrict__ in, const float* __restrict__ anchors,
    float* __restrict__ out)
{
    __shared__ float lds[TILE * NCH];   // 21760 B -> 7 blocks/CU

    const int t = threadIdx.x;

    float4 va[LITERS], vb[LITERS];

    auto load_tile = [&](float4 (&vv)[LITERS], int g) {
        int ba   = g / TPB;
        int tile = g - ba * TPB;
        int s0   = tile * TILE;
        const float* inb = in + (long)ba * (NCH * GG);
        #pragma unroll
        for (int i = 0; i < LITERS; ++i) {
            int idx = t + i * THREADS;
            int c   = idx >> 4;
            int q   = idx & 15;
            int pos = s0 + q * 4;
            if (idx < LOAD_UNITS && pos < GG)
                vv[i] = *reinterpret_cast<const float4*>(&inb[(long)c * GG + pos]);
        }
    };

    // transform va/vb -> LDS, then LDS -> global (two barriers inside)
    auto process_tile = [&](float4 (&vv)[LITERS], int g) {
        int ba   = g / TPB;
        int tile = g - ba * TPB;
        int a    = ba % NA;
        int s0   = tile * TILE;
        float aw = anchors[2 * a];
        float ah = anchors[2 * a + 1];
        #pragma unroll
        for (int i = 0; i < LITERS; ++i) {
            int idx = t + i * THREADS;
            int c   = idx >> 4;
            int q   = idx & 15;
            int pos = s0 + q * 4;
            if (idx < LOAD_UNITS && pos < GG) {
                float r[4] = {vv[i].x, vv[i].y, vv[i].z, vv[i].w};
                if (c == 0) {
                    #pragma unroll
                    for (int k = 0; k < 4; ++k) {
                        int p = pos + k;
                        float gx = (float)(p - (p / GDIM) * GDIM);
                        r[k] = (fast_sigmoid(r[k]) + gx) * 8.0f;
                    }
                } else if (c == 1) {
                    #pragma unroll
                    for (int k = 0; k < 4; ++k) {
                        int p = pos + k;
                        float gy = (float)(p / GDIM);
                        r[k] = (fast_sigmoid(r[k]) + gy) * 8.0f;
                    }
                } else if (c == 2) {
                    #pragma unroll
                    for (int k = 0; k < 4; ++k) r[k] = __expf(r[k]) * aw;
                } else if (c == 3) {
                    #pragma unroll
                    for (int k = 0; k < 4; ++k) r[k] = __expf(r[k]) * ah;
                } else {
                    #pragma unroll
                    for (int k = 0; k < 4; ++k) r[k] = fast_sigmoid(r[k]);
                }
                #pragma unroll
                for (int k = 0; k < 4; ++k)
                    lds[(q * 4 + k) * NCH + c] = r[k];
            }
        }

        __syncthreads();

        int valid = (GG - s0 < TILE) ? (GG - s0) : TILE;  // 64 or 16
        int n4    = valid * NCH / 4;                       // 1360 or 340
        float4* __restrict__ outv =
            reinterpret_cast<float4*>(out + ((long)ba * GG + s0) * NCH);
        const float4* ldsv = reinterpret_cast<const float4*>(lds);
        #pragma unroll
        for (int i = 0; i < LITERS; ++i) {
            int f4 = t + i * THREADS;
            if (f4 < n4)
                outv[f4] = ldsv[f4];   // ds_read_b128 + global_store_dwordx4
        }

        __syncthreads();               // LDS drained before next overwrite
    };

    // Every block owns 2 or 3 tiles (NT/GRID = 2.4375).
    int g = blockIdx.x;
    load_tile(va, g);
    while (true) {
        int gB = g + GRID;
        if (gB < NT) load_tile(vb, gB);    // issue B before processing A
        process_tile(va, g);
        if (gB >= NT) break;
        int gA = gB + GRID;
        if (gA < NT) load_tile(va, gA);    // issue next A before processing B
        process_tile(vb, gB);
        if (gA >= NT) break;
        g = gA;
    }
}

extern "C" void kernel_launch(void* const* d_in, const int* in_sizes, int n_in,
                              void* d_out, int out_size, void* d_ws, size_t ws_size,
                              hipStream_t stream) {
    const float* pred    = (const float*)d_in[0];
    const float* anchors = (const float*)d_in[1];
    float* out           = (float*)d_out;

    yolo_kernel<<<dim3(GRID), dim3(THREADS), 0, stream>>>(pred, anchors, out);
}

// Round 10
// 37.688 us; speedup vs baseline: 1.0089x; 1.0089x over previous
//
#include <hip/hip_runtime.h>

// YOLO layer: input [B=16, A*C=255, G=76, G=76] f32, anchors [3,2] f32.
// Output [B, A*G*G=17328, C=85] f32.
//   c=0: (sigmoid+gx)*8, c=1: (sigmoid+gy)*8, c=2: exp*aw, c=3: exp*ah,
//   c>=4: sigmoid   (anchor/stride scaling folded: (e^w * aw/8)*8 == e^w*aw)
//
// WAVE-AUTONOMOUS redesign (R9): every __syncthreads emits
// s_waitcnt vmcnt(0) -> all cross-wave-barrier structures cap at ~36us
// (R3/R7/R8 evidence). Fix: each wave owns a private 16-pos x 85-ch LDS
// slice -> transpose needs only wave-local lgkmcnt ordering. ZERO barriers,
// waves slip freely, no forced drains, 28 waves/CU TLP.
//   5776 = 361*16 exactly -> no partial wave-tiles.
//   load: 16 aligned 64B lines per instr (full utilization)
//   ds_write stride-85 (<=3 lanes/bank), ds_read_b128 flat (free)
//   store: contiguous dwordx4, 5440B per wave-tile
// Lessons kept: plain stores (R5), HIP float4 (R6), v_exp/v_rcp (R7).

#define GDIM 76
#define GG 5776            // 76*76 = 361*16
#define NA 3
#define NCH 85
#define W 16               // spatial positions per wave-tile
#define THREADS 256        // 4 waves
#define TPW 361            // wave-tiles per (b,a): 5776/16
#define NTW (TPW * NA * 16)   // 17328 wave-tiles
#define UNITS (NCH * (W / 4)) // 340 float4 units per wave-tile
#define WITERS 6              // ceil(340/64)
#define GRID 1792             // 7 blocks/CU (LDS: 7*22016 = 154KB <= 160KB)
#define NWAVES (GRID * 4)     // 7168

__device__ __forceinline__ float fast_sigmoid(float x) {
    // 1/(1+exp(-x)): v_exp_f32 + v_add + v_rcp_f32. ~2 ulp; threshold ~496.
    return __builtin_amdgcn_rcpf(1.0f + __expf(-x));
}

__global__ __launch_bounds__(THREADS) void yolo_kernel(
    const float* __restrict__ in, const float* __restrict__ anchors,
    float* __restrict__ out)
{
    __shared__ float lds[4][W * NCH];   // 4 x 5440B private wave slices

    const int wl  = threadIdx.x >> 6;   // wave within block
    const int l   = threadIdx.x & 63;   // lane
    float* slice  = &lds[wl][0];
    const int wid = blockIdx.x * 4 + wl;

    for (int g = wid; g < NTW; g += NWAVES) {
        const int ba   = g / TPW;            // b*3 + a
        const int tile = g - ba * TPW;
        const int a    = ba % NA;
        const int s0   = tile * W;
        const float aw = anchors[2 * a];
        const float ah = anchors[2 * a + 1];
        const float* inb = in + (long)ba * (NCH * GG) + s0;

        float4 v[WITERS];

        // load: unit u -> channel c = u>>2, quad q = u&3 (4 quads = 16 pos)
        #pragma unroll
        for (int i = 0; i < WITERS; ++i) {
            int u = l + i * 64;
            if (u < UNITS) {
                int c = u >> 2, q = u & 3;
                v[i] = *reinterpret_cast<const float4*>(&inb[(long)c * GG + q * 4]);
            }
        }

        // transform -> private LDS slice [pos][85]
        #pragma unroll
        for (int i = 0; i < WITERS; ++i) {
            int u = l + i * 64;
            if (u < UNITS) {
                int c = u >> 2, q = u & 3;
                float r[4] = {v[i].x, v[i].y, v[i].z, v[i].w};
                if (c == 0) {
                    #pragma unroll
                    for (int k = 0; k < 4; ++k) {
                        int p = s0 + q * 4 + k;
                        float gx = (float)(p - (p / GDIM) * GDIM);
                        r[k] = (fast_sigmoid(r[k]) + gx) * 8.0f;
                    }
                } else if (c == 1) {
                    #pragma unroll
                    for (int k = 0; k < 4; ++k) {
                        int p = s0 + q * 4 + k;
                        float gy = (float)(p / GDIM);
                        r[k] = (fast_sigmoid(r[k]) + gy) * 8.0f;
                    }
                } else if (c == 2) {
                    #pragma unroll
                    for (int k = 0; k < 4; ++k) r[k] = __expf(r[k]) * aw;
                } else if (c == 3) {
                    #pragma unroll
                    for (int k = 0; k < 4; ++k) r[k] = __expf(r[k]) * ah;
                } else {
                    #pragma unroll
                    for (int k = 0; k < 4; ++k) r[k] = fast_sigmoid(r[k]);
                }
                #pragma unroll
                for (int k = 0; k < 4; ++k)
                    slice[(q * 4 + k) * NCH + c] = r[k];
            }
        }
        // wave-local lgkmcnt ordering only -- no barrier

        // store: flat [pos][85] slice == output layout, contiguous
        float4* __restrict__ outv =
            reinterpret_cast<float4*>(out + ((long)ba * GG + s0) * NCH);
        const float4* sv = reinterpret_cast<const float4*>(slice);
        #pragma unroll
        for (int i = 0; i < WITERS; ++i) {
            int f4 = l + i * 64;
            if (f4 < UNITS)
                outv[f4] = sv[f4];   // ds_read_b128 + global_store_dwordx4
        }
    }
}

extern "C" void kernel_launch(void* const* d_in, const int* in_sizes, int n_in,
                              void* d_out, int out_size, void* d_ws, size_t ws_size,
                              hipStream_t stream) {
    const float* pred    = (const float*)d_in[0];
    const float* anchors = (const float*)d_in[1];
    float* out           = (float*)d_out;

    yolo_kernel<<<dim3(GRID), dim3(THREADS), 0, stream>>>(pred, anchors, out);
}

// Round 11
// 33.781 us; speedup vs baseline: 1.1256x; 1.1157x over previous
//
#include <hip/hip_runtime.h>

// YOLO layer: input [B=16, A*C=255, G=76, G=76] f32, anchors [3,2] f32.
// Output [B, A*G*G=17328, C=85] f32.
//   c=0: (sigmoid+gx)*8, c=1: (sigmoid+gy)*8, c=2: exp*aw, c=3: exp*ah,
//   c>=4: sigmoid   (anchor/stride scaling folded: (e^w * aw/8)*8 == e^w*aw)
//
// R10: read-burst-length experiment. R9(64B chunks)=37.7 < R7(256B)=35.9
// suggests longer contiguous reads -> better DRAM efficiency. TILE 64->128:
// 512B contiguous per channel per tile, half the barrier events.
// Trade: LDS 43.5KB -> 3 blocks/CU (24 waves vs 28); ds_write stride-85
// conflict 2-way -> 4-way (1.58x on the write phase only).
// Structure otherwise identical to R7 (best, 35.9us): persistent blocks,
// single-buffer prefetch, __syncthreads, HIP float4, v_exp/v_rcp.

#define GDIM 76
#define GG 5776            // 76*76 (divisible by 4)
#define NA 3
#define NCH 85
#define TILE 128           // spatial positions per block-tile
#define THREADS 512        // 8 waves
#define LOAD_UNITS (NCH * (TILE / 4))  // 2720 float4 units per tile
#define LITERS 6                       // ceil(2720/512)
#define TPB 46                         // tiles per (b,a): ceil(5776/128)
#define NT (TPB * NA * 16)             // 2208 total tiles
#define GRID 768                       // 3 blocks/CU * 256 CUs (LDS cap)

__device__ __forceinline__ float fast_sigmoid(float x) {
    // 1/(1+exp(-x)): v_exp_f32 + v_add + v_rcp_f32. ~2 ulp; threshold ~496.
    return __builtin_amdgcn_rcpf(1.0f + __expf(-x));
}

__global__ __launch_bounds__(THREADS) void yolo_kernel(
    const float* __restrict__ in, const float* __restrict__ anchors,
    float* __restrict__ out)
{
    __shared__ float lds[TILE * NCH];   // 43520 B -> 3 blocks/CU

    const int t = threadIdx.x;

    float4 v[LITERS];

    auto load_tile = [&](int g) {
        int ba   = g / TPB;
        int tile = g - ba * TPB;
        int s0   = tile * TILE;
        const float* inb = in + (long)ba * (NCH * GG);
        #pragma unroll
        for (int i = 0; i < LITERS; ++i) {
            int idx = t + i * THREADS;
            int c   = idx >> 5;         // channel (32 quads per channel)
            int q   = idx & 31;
            int pos = s0 + q * 4;
            if (idx < LOAD_UNITS && pos < GG)
                v[i] = *reinterpret_cast<const float4*>(&inb[(long)c * GG + pos]);
        }
    };

    auto transform_write = [&](int g) {
        int ba   = g / TPB;
        int tile = g - ba * TPB;
        int a    = ba % NA;
        int s0   = tile * TILE;
        float aw = anchors[2 * a];
        float ah = anchors[2 * a + 1];
        #pragma unroll
        for (int i = 0; i < LITERS; ++i) {
            int idx = t + i * THREADS;
            int c   = idx >> 5;
            int q   = idx & 31;
            int pos = s0 + q * 4;
            if (idx < LOAD_UNITS && pos < GG) {
                float r[4] = {v[i].x, v[i].y, v[i].z, v[i].w};
                if (c == 0) {
                    #pragma unroll
                    for (int k = 0; k < 4; ++k) {
                        int p = pos + k;
                        float gx = (float)(p - (p / GDIM) * GDIM);
                        r[k] = (fast_sigmoid(r[k]) + gx) * 8.0f;
                    }
                } else if (c == 1) {
                    #pragma unroll
                    for (int k = 0; k < 4; ++k) {
                        int p = pos + k;
                        float gy = (float)(p / GDIM);
                        r[k] = (fast_sigmoid(r[k]) + gy) * 8.0f;
                    }
                } else if (c == 2) {
                    #pragma unroll
                    for (int k = 0; k < 4; ++k) r[k] = __expf(r[k]) * aw;
                } else if (c == 3) {
                    #pragma unroll
                    for (int k = 0; k < 4; ++k) r[k] = __expf(r[k]) * ah;
                } else {
                    #pragma unroll
                    for (int k = 0; k < 4; ++k) r[k] = fast_sigmoid(r[k]);
                }
                #pragma unroll
                for (int k = 0; k < 4; ++k)
                    lds[(q * 4 + k) * NCH + c] = r[k];
            }
        }
    };

    auto store_tile = [&](int g) {
        int ba    = g / TPB;
        int tile  = g - ba * TPB;
        int s0    = tile * TILE;
        int valid = (GG - s0 < TILE) ? (GG - s0) : TILE;  // 128 or 16
        int n4    = valid * NCH / 4;                       // 2720 or 340
        float4* __restrict__ outv =
            reinterpret_cast<float4*>(out + ((long)ba * GG + s0) * NCH);
        const float4* ldsv = reinterpret_cast<const float4*>(lds);
        #pragma unroll
        for (int i = 0; i < LITERS; ++i) {
            int f4 = t + i * THREADS;
            if (f4 < n4)
                outv[f4] = ldsv[f4];   // ds_read_b128 + global_store_dwordx4
        }
    };

    int g = blockIdx.x;
    load_tile(g);                       // prologue (every block has >=2 tiles)
    for (; g < NT; g += GRID) {
        transform_write(g);             // consumes v (vmcnt wait), fills LDS
        __syncthreads();
        int gn = g + GRID;
        if (gn < NT) load_tile(gn);     // issue next-tile loads
        store_tile(g);                  // LDS -> global
        __syncthreads();                // LDS drained before next overwrite
    }
}

extern "C" void kernel_launch(void* const* d_in, const int* in_sizes, int n_in,
                              void* d_out, int out_size, void* d_ws, size_t ws_size,
                              hipStream_t stream) {
    const float* pred    = (const float*)d_in[0];
    const float* anchors = (const float*)d_in[1];
    float* out           = (float*)d_out;

    yolo_kernel<<<dim3(GRID), dim3(THREADS), 0, stream>>>(pred, anchors, out);
}